// Round 13
// baseline (267.151 us; speedup 1.0000x reference)
//
#include <hip/hip_runtime.h>

#define HW 1024
#define TWO_PI_F 6.28318530717958647692f
#define NSLOT 64   // atomic spreading: 64 slots per accumulator, 5 accumulators
#define COLS_NBLK 2056u   // 257 x 8 grid

typedef float v2f __attribute__((ext_vector_type(2)));
typedef int   i2v __attribute__((ext_vector_type(2)));

__device__ __forceinline__ v2f mkv2(float a, float b){ v2f r; r.x = a; r.y = b; return r; }
__device__ __forceinline__ v2f v2s(float s){ v2f r; r.x = s; r.y = s; return r; }

__device__ __forceinline__ float2 cmulf(float2 a, float2 b){
  return make_float2(a.x*b.x - a.y*b.y, a.x*b.y + a.y*b.x);
}
__device__ __forceinline__ float fsqrt(float x){ return __builtin_amdgcn_sqrtf(x); }

// fast |atan2|: caller passes ay = |y| >= 0. Saves the final sign-select.
__device__ __forceinline__ float fast_atan2_abs(float ay, float x){
  float ax = fabsf(x);
  float mx = fmaxf(ax, ay), mn = fminf(ax, ay);
  float a  = mn * __builtin_amdgcn_rcpf(fmaxf(mx, 1e-37f));
  float s  = a * a;
  float r  = ((((0.0208351f*s - 0.085133f)*s + 0.180141f)*s - 0.3302995f)*s
              + 0.999866f) * a;
  r = (ay > ax) ? 1.57079632679f - r : r;
  return (x < 0.f) ? 3.14159265359f - r : r;
}

// 256-thread block reduction (4 waves of 64), float
__device__ __forceinline__ float block_reduce_add_f(float v, float* sc){
  int tid = threadIdx.x;
  #pragma unroll
  for (int o = 32; o > 0; o >>= 1) v += __shfl_down(v, o, 64);
  __syncthreads();
  if ((tid & 63) == 0) sc[tid >> 6] = v;
  __syncthreads();
  return sc[0] + sc[1] + sc[2] + sc[3];
}

// ---------------------------------------------------------------------------
// Spatial half (R17/R21-verified body, one dispatch).
// ---------------------------------------------------------------------------
__global__ __launch_bounds__(256, 4)
void spatial_kernel(const float* __restrict__ pred, const float* __restrict__ targ,
                    const float* __restrict__ mask, double* __restrict__ acc){
  __shared__ v2f spt[36*44];               // (pred, targ) halo tile, stride 44
  __shared__ v2f pmt[34*35];               // union: smkf float[38*41] / (pmag,tmag)
  __shared__ unsigned long long mrow[38];
  __shared__ float sc[4];
  float* const smkf = (float*)pmt;         // 1558 floats = 6232 B <= 9520 B

  const int tid = threadIdx.x;
  const int x0 = blockIdx.x << 5, y0 = blockIdx.y << 5;
  const int z = blockIdx.z;
  const size_t ib = (size_t)z * ((size_t)HW * HW);
  const bool interior = ((unsigned)(blockIdx.x - 1) < 30u) &&
                        ((unsigned)(blockIdx.y - 1) < 30u);

  if (interior){
    const float* pb = pred + ib;
    const float* tb = targ + ib;
    for (int i = tid; i < 360; i += 256){        // 36 rows x 10 float4 (40 cols)
      int a = i / 10, b = i % 10;
      size_t off = (size_t)(y0 - 2 + a) * HW + (x0 - 4 + 4*b);
      float4 pv = *(const float4*)(pb + off);
      float4 tv = *(const float4*)(tb + off);
      int o = a*44 + 4*b;
      spt[o+0] = mkv2(pv.x, tv.x);
      spt[o+1] = mkv2(pv.y, tv.y);
      spt[o+2] = mkv2(pv.z, tv.z);
      spt[o+3] = mkv2(pv.w, tv.w);
    }
    const float* mb = mask + ib;
    for (int i = tid; i < 380; i += 256){        // 38 rows x 10 float4
      int a = i / 10, b = i % 10;
      size_t off = (size_t)(y0 - 3 + a) * HW + (x0 - 4 + 4*b);
      float4 v = *(const float4*)(mb + off);
      int o = a*41 + 4*b;
      smkf[o]=v.x; smkf[o+1]=v.y; smkf[o+2]=v.z; smkf[o+3]=v.w;
    }
  } else {
    for (int i = tid; i < 1296; i += 256){
      int a = i / 36, b = i % 36;
      int gy = y0 - 2 + a, gx = x0 - 2 + b;
      float pv = 0.f, tv = 0.f;
      if ((unsigned)gy < HW && (unsigned)gx < HW){
        size_t idx = ib + (size_t)gy * HW + gx;
        pv = pred[idx]; tv = targ[idx];
      }
      spt[a*44 + b + 2] = mkv2(pv, tv);
    }
    for (int i = tid; i < 1444; i += 256){
      int a = i / 38, b = i % 38;
      int gy = y0 - 3 + a, gx = x0 - 3 + b;
      float v = 0.f;
      if ((unsigned)gy < HW && (unsigned)gx < HW) v = mask[ib + (size_t)gy * HW + gx];
      smkf[a*41 + b + 1] = v;
    }
  }
  __syncthreads();

  // wave-parallel mask rows via ballot (lanes 0..37 active per row)
  {
    const int wv = tid >> 6, lane = tid & 63;
    for (int r = wv; r < 38; r += 4){
      float val = (lane < 38) ? smkf[r*41 + 1 + lane] : 0.f;
      unsigned long long m = __ballot(val > 0.5f);
      if (lane == 0) mrow[r] = m;
    }
  }
  __syncthreads();                              // smkf reads done; pmt reuse ok

  if (interior){
    for (int i = tid; i < 1156; i += 256){      // no bounds checks: always in-range
      int iy = i / 34, ix = i % 34;
      int o = iy*44 + ix + 2;
      v2f a00=spt[o],    a01=spt[o+1],  a02=spt[o+2];
      v2f a10=spt[o+44],                a12=spt[o+46];
      v2f a20=spt[o+88], a21=spt[o+89], a22=spt[o+90];
      v2f gx = (a02 + v2s(2.f)*a12 + a22) - (a00 + v2s(2.f)*a10 + a20);
      v2f gy = (a20 + v2s(2.f)*a21 + a22) - (a00 + v2s(2.f)*a01 + a02);
      v2f m2 = gx*gx + gy*gy + v2s(1e-8f);
      pmt[iy*35+ix] = mkv2(fsqrt(m2.x), fsqrt(m2.y));
    }
  } else {
    for (int i = tid; i < 1156; i += 256){
      int iy = i / 34, ix = i % 34;
      int gy = y0 - 1 + iy, gx = x0 - 1 + ix;
      v2f out = v2s(0.f);
      if ((unsigned)gy < HW && (unsigned)gx < HW){
        int o = iy*44 + ix + 2;
        v2f a00=spt[o],    a01=spt[o+1],  a02=spt[o+2];
        v2f a10=spt[o+44],                a12=spt[o+46];
        v2f a20=spt[o+88], a21=spt[o+89], a22=spt[o+90];
        v2f gxv = (a02 + v2s(2.f)*a12 + a22) - (a00 + v2s(2.f)*a10 + a20);
        v2f gyv = (a20 + v2s(2.f)*a21 + a22) - (a00 + v2s(2.f)*a01 + a02);
        v2f m2 = gxv*gxv + gyv*gyv + v2s(1e-8f);
        out = mkv2(fsqrt(m2.x), fsqrt(m2.y));
      }
      pmt[iy*35+ix] = out;
    }
  }
  __syncthreads();

  const int ty = tid >> 5, tx = tid & 31;
  const int r0 = ty << 2;

  // packed counts: cp[j] = c1 | c2<<8 | c3<<16 (vertical sums can't carry)
  int cp[10];
  #pragma unroll
  for (int j = 0; j < 10; j++){
    unsigned w = (unsigned)(mrow[r0 + j] >> tx);
    int c3 = __popc(w & 0x7Fu);
    int c2 = __popc((w >> 1) & 0x1Fu);
    int c1 = __popc((w >> 2) & 0x7u);
    cp[j] = c1 | (c2 << 8) | (c3 << 16);
  }

  v2f PQ[3][3], AB[3][3];
  #pragma unroll
  for (int rr = 0; rr < 2; rr++)
    #pragma unroll
    for (int cc = 0; cc < 3; cc++){
      PQ[rr][cc] = spt[(r0+1+rr)*44 + tx+3+cc];
      AB[rr][cc] = pmt[(r0+rr)*35 + tx+cc];
    }

  // per-row rolling state: slot r <-> PQ row (r0+1+r) / AB row (r0+r)
  v2f wR[6], wA[6];      // (1,2,1)-weighted row sums (sobel-y / slope-y)
  float uR[6], qR[6];    // plain and squared row sums of pred (smooth)
  #pragma unroll
  for (int r = 0; r < 2; r++){
    wR[r] = PQ[r][0] + v2s(2.f)*PQ[r][1] + PQ[r][2];
    float p0 = PQ[r][0].x, p1 = PQ[r][1].x, p2 = PQ[r][2].x;
    uR[r] = p0 + p1 + p2;
    qR[r] = fmaf(p0, p0, fmaf(p1, p1, p2*p2));
    wA[r] = AB[r][0] + v2s(2.f)*AB[r][1] + AB[r][2];
  }

  float accg = 0.f, accs = 0.f, accl = 0.f;
  #pragma unroll
  for (int k = 0; k < 4; k++){
    #pragma unroll
    for (int cc = 0; cc < 3; cc++){
      PQ[2][cc] = spt[(r0+k+3)*44 + tx+3+cc];
      AB[2][cc] = pmt[(r0+k+2)*35 + tx+cc];
    }
    {
      wR[k+2] = PQ[2][0] + v2s(2.f)*PQ[2][1] + PQ[2][2];
      float p0 = PQ[2][0].x, p1 = PQ[2][1].x, p2 = PQ[2][2].x;
      uR[k+2] = p0 + p1 + p2;
      qR[k+2] = fmaf(p0, p0, fmaf(p1, p1, p2*p2));
      wA[k+2] = AB[2][0] + v2s(2.f)*AB[2][1] + AB[2][2];
    }

    v2f gxv = (PQ[0][2] + v2s(2.f)*PQ[1][2] + PQ[2][2]) - (PQ[0][0] + v2s(2.f)*PQ[1][0] + PQ[2][0]);
    v2f gyv = wR[k+2] - wR[k];
    v2f cvv = v2s(4.f)*PQ[1][1] - PQ[0][1] - PQ[1][0] - PQ[1][2] - PQ[2][1];

    float sd = fabsf(AB[1][1].x - AB[1][1].y);
    float x1 = gxv.x + 1e-8f, y1 = gyv.x;
    float x2 = gxv.y + 1e-8f, y2 = gyv.y;
    float dd = fast_atan2_abs(fabsf(y1*x2 - x1*y2), x1*x2 + y1*y2);
    float cd = fabsf(cvv.x - cvv.y);

    int s1p = cp[k+2] + cp[k+3] + cp[k+4];
    int s2p = s1p + cp[k+1] + cp[k+5];
    int s3p = s2p + cp[k]   + cp[k+6];
    int s1 = s1p & 0xFF;
    int s2 = (s2p >> 8) & 0xFF;
    int s3 = s3p >> 16;
    float w1 = ((unsigned)(s1 - 1) <  8u) ? 1.f : 0.f;
    float w2 = ((unsigned)(s2 - 1) < 24u) ? 1.f : 0.f;
    float w3 = ((unsigned)(s3 - 1) < 48u) ? 1.f : 0.f;
    float wa = fmaf(0.5f, w2 + w3, w1);

    accg = fmaf(wa, sd + dd + 2.f*cd, accg);

    float s9 = uR[k] + uR[k+1] + uR[k+2];
    float s9q = qR[k] + qR[k+1] + qR[k+2];
    float lm = s9 * (1.f/9.f), lq = s9q * (1.f/9.f);
    accs = fmaf(fsqrt(fmaxf(lq - lm*lm, 1e-8f)), w1, accs);

    v2f px = (AB[0][2] + v2s(2.f)*AB[1][2] + AB[2][2]) - (AB[0][0] + v2s(2.f)*AB[1][0] + AB[2][0]);
    v2f py = wA[k+2] - wA[k];
    v2f ch2 = px*px + py*py + v2s(1e-8f);
    accl = fmaf(fabsf(fsqrt(ch2.x) - fsqrt(ch2.y)), w1, accl);

    if (k < 3){
      #pragma unroll
      for (int cc = 0; cc < 3; cc++){
        PQ[0][cc] = PQ[1][cc]; PQ[1][cc] = PQ[2][cc];
        AB[0][cc] = AB[1][cc]; AB[1][cc] = AB[2][cc];
      }
    }
  }

  float g  = block_reduce_add_f(accg, sc);
  float sm = block_reduce_add_f(accs, sc);
  float sl = block_reduce_add_f(accl, sc);
  if (tid == 0){
    int slot = (blockIdx.x + blockIdx.y * 7 + z * 13) & (NSLOT - 1);
    atomicAdd(&acc[0*NSLOT + slot], (double)g);
    atomicAdd(&acc[1*NSLOT + slot], (double)sm);
    atomicAdd(&acc[2*NSLOT + slot], (double)sl);
  }
}

// ---------------------------------------------------------------------------
// ALL-VALU lane exchanges (R20-verified primitives).
// ---------------------------------------------------------------------------
template<int CTRL>
__device__ __forceinline__ float xordpp(float x){
  int xi = __float_as_int(x);
  return __int_as_float(__builtin_amdgcn_update_dpp(xi, xi, CTRL, 0xF, 0xF, true));
}
__device__ __forceinline__ float xor4v(float x){
  int xi = __float_as_int(x);
  int t1 = __builtin_amdgcn_update_dpp(xi, xi, 0x104, 0xF, 0x5, false); // SHL4 -> banks 0,2
  int t2 = __builtin_amdgcn_update_dpp(t1, xi, 0x114, 0xF, 0xA, false); // SHR4 -> banks 1,3
  return __int_as_float(t2);
}

#define FC 0.70710678118654752f
#define FC1 0.92387953251128676f
#define FS1 0.38268343236508977f

__device__ __forceinline__ void bfly(float2& a, float2& b){
  float tx = b.x, ty = b.y;
  b.x = a.x - tx; b.y = a.y - ty;
  a.x += tx;      a.y += ty;
}
__device__ __forceinline__ void cmul_c(float2& b, float wr, float wi){
  float tx = wr*b.x - wi*b.y, ty = wr*b.y + wi*b.x;
  b.x = tx; b.y = ty;
}
__device__ __forceinline__ void rotmi(float2& b){   // b *= -i
  float t = b.x; b.x = b.y; b.y = -t;
}

__device__ __forceinline__ void fft16_reg(float2* v){
  float2 y[16];
  y[0]=v[0];  y[1]=v[8];  y[2]=v[4];  y[3]=v[12];
  y[4]=v[2];  y[5]=v[10]; y[6]=v[6];  y[7]=v[14];
  y[8]=v[1];  y[9]=v[9];  y[10]=v[5]; y[11]=v[13];
  y[12]=v[3]; y[13]=v[11];y[14]=v[7]; y[15]=v[15];
  #pragma unroll
  for (int g = 0; g < 8; g++) bfly(y[2*g], y[2*g+1]);
  #pragma unroll
  for (int g = 0; g < 4; g++){
    int b = 4*g;
    bfly(y[b], y[b+2]);
    rotmi(y[b+3]); bfly(y[b+1], y[b+3]);
  }
  #pragma unroll
  for (int g = 0; g < 2; g++){
    int b = 8*g;
    bfly(y[b], y[b+4]);
    cmul_c(y[b+5],  FC, -FC); bfly(y[b+1], y[b+5]);
    rotmi(y[b+6]);            bfly(y[b+2], y[b+6]);
    cmul_c(y[b+7], -FC, -FC); bfly(y[b+3], y[b+7]);
  }
  bfly(y[0], y[8]);
  cmul_c(y[9],   FC1, -FS1); bfly(y[1], y[9]);
  cmul_c(y[10],  FC,  -FC);  bfly(y[2], y[10]);
  cmul_c(y[11],  FS1, -FC1); bfly(y[3], y[11]);
  rotmi(y[12]);              bfly(y[4], y[12]);
  cmul_c(y[13], -FS1, -FC1); bfly(y[5], y[13]);
  cmul_c(y[14], -FC,  -FC);  bfly(y[6], y[14]);
  cmul_c(y[15], -FC1, -FS1); bfly(y[7], y[15]);
  #pragma unroll
  for (int j = 0; j < 16; j++) v[j] = y[j];
}

// R25: raw-HW twiddle gen. v_sin/v_cos take REVOLUTIONS; our angle is exactly
// -idx/1024 revolutions (in the accurate range) -> 1 V-op per component,
// no libm argument reduction (R24's sincosf cost ~+8.6 us across the FFTs).
__device__ __forceinline__ float2 twf(int idx){
  float a = (float)idx * (-1.0f/1024.0f);      // revolutions
  return make_float2(__builtin_amdgcn_cosf(a), __builtin_amdgcn_sinf(a));
}

// ---------------------------------------------------------------------------
// Natural-lane DIT (R22-verified): logical lane L = brev6(p); natural input
// order; six verified exchange primitives in reversed order; output
// X[brev6(p)+64j].
// ---------------------------------------------------------------------------
__device__ __forceinline__ void fft1024_wave(float2* v, int lane /*logical L*/){
  const float2 tw1 = twf((lane & 1) << 8);
  const float2 tw2 = twf((lane & 3) << 7);
  const float2 tw3 = twf((lane & 7) << 6);
  const float2 tw4 = twf((lane & 15) << 5);
  const float2 tw5 = twf((lane & 31) << 4);
  const float2 wq  = twf(lane);

  // stage 0 (logical h=1 -> physical 32): permlane32 fused, w=1
  {
    const float sgn = (lane & 1) ? -1.f : 1.f;
    #pragma unroll
    for (int j = 0; j < 16; j++){
      i2v px = __builtin_amdgcn_permlane32_swap(__float_as_int(v[j].x), __float_as_int(v[j].x), false, false);
      i2v py = __builtin_amdgcn_permlane32_swap(__float_as_int(v[j].y), __float_as_int(v[j].y), false, false);
      v[j].x = fmaf(sgn, __int_as_float(px.y), __int_as_float(px.x));
      v[j].y = fmaf(sgn, __int_as_float(py.y), __int_as_float(py.x));
    }
  }
  // stage 1 (logical h=2 -> physical 16): permlane16 fused
  {
    const bool up = (lane & 2) != 0;
    const float ewx = up ? tw1.x : 1.f, ewy = up ? tw1.y : 0.f;
    const float sgn = up ? -1.f : 1.f;
    #pragma unroll
    for (int j = 0; j < 16; j++){
      float tx = ewx*v[j].x - ewy*v[j].y;
      float ty = ewx*v[j].y + ewy*v[j].x;
      i2v px = __builtin_amdgcn_permlane16_swap(__float_as_int(tx), __float_as_int(tx), false, false);
      i2v py = __builtin_amdgcn_permlane16_swap(__float_as_int(ty), __float_as_int(ty), false, false);
      v[j].x = fmaf(sgn, __int_as_float(px.y), __int_as_float(px.x));
      v[j].y = fmaf(sgn, __int_as_float(py.y), __int_as_float(py.x));
    }
  }
  // stage 2 (logical h=4 -> physical 8): ROW_ROR:8
  {
    const bool up = (lane & 4) != 0;
    const float ewx = up ? tw2.x : 1.f, ewy = up ? tw2.y : 0.f;
    const float sgn = up ? -1.f : 1.f;
    #pragma unroll
    for (int j = 0; j < 16; j++){
      float tx = ewx*v[j].x - ewy*v[j].y;
      float ty = ewx*v[j].y + ewy*v[j].x;
      v[j].x = fmaf(sgn, tx, xordpp<0x128>(tx));
      v[j].y = fmaf(sgn, ty, xordpp<0x128>(ty));
    }
  }
  // stage 3 (logical h=8 -> physical 4): bank-masked DPP pair
  {
    const bool up = (lane & 8) != 0;
    const float ewx = up ? tw3.x : 1.f, ewy = up ? tw3.y : 0.f;
    const float sgn = up ? -1.f : 1.f;
    #pragma unroll
    for (int j = 0; j < 16; j++){
      float tx = ewx*v[j].x - ewy*v[j].y;
      float ty = ewx*v[j].y + ewy*v[j].x;
      v[j].x = fmaf(sgn, tx, xor4v(tx));
      v[j].y = fmaf(sgn, ty, xor4v(ty));
    }
  }
  // stage 4 (logical h=16 -> physical 2): quad_perm xor2
  {
    const bool up = (lane & 16) != 0;
    const float ewx = up ? tw4.x : 1.f, ewy = up ? tw4.y : 0.f;
    const float sgn = up ? -1.f : 1.f;
    #pragma unroll
    for (int j = 0; j < 16; j++){
      float tx = ewx*v[j].x - ewy*v[j].y;
      float ty = ewx*v[j].y + ewy*v[j].x;
      v[j].x = fmaf(sgn, tx, xordpp<0x4E>(tx));
      v[j].y = fmaf(sgn, ty, xordpp<0x4E>(ty));
    }
  }
  // stage 5 (logical h=32 -> physical 1): quad_perm xor1
  {
    const bool up = (lane & 32) != 0;
    const float ewx = up ? tw5.x : 1.f, ewy = up ? tw5.y : 0.f;
    const float sgn = up ? -1.f : 1.f;
    #pragma unroll
    for (int j = 0; j < 16; j++){
      float tx = ewx*v[j].x - ewy*v[j].y;
      float ty = ewx*v[j].y + ewy*v[j].x;
      v[j].x = fmaf(sgn, tx, xordpp<0xB1>(tx));
      v[j].y = fmaf(sgn, ty, xordpp<0xB1>(ty));
    }
  }
  // per-slot twiddle: v[j] *= wq^j; log-depth powers
  float2 w2 = cmulf(wq, wq);
  float2 w3 = cmulf(w2, wq);
  float2 w4 = cmulf(w2, w2);
  float2 w5 = cmulf(w3, w2);
  float2 w6 = cmulf(w3, w3);
  float2 w7 = cmulf(w4, w3);
  float2 w8 = cmulf(w4, w4);
  v[1]  = cmulf(v[1],  wq);
  v[2]  = cmulf(v[2],  w2);
  v[3]  = cmulf(v[3],  w3);
  v[4]  = cmulf(v[4],  w4);
  v[5]  = cmulf(v[5],  w5);
  v[6]  = cmulf(v[6],  w6);
  v[7]  = cmulf(v[7],  w7);
  v[8]  = cmulf(v[8],  w8);
  v[9]  = cmulf(cmulf(v[9],  w8), wq);
  v[10] = cmulf(cmulf(v[10], w8), w2);
  v[11] = cmulf(cmulf(v[11], w8), w3);
  v[12] = cmulf(cmulf(v[12], w8), w4);
  v[13] = cmulf(cmulf(v[13], w8), w5);
  v[14] = cmulf(cmulf(v[14], w8), w6);
  v[15] = cmulf(cmulf(v[15], w8), w7);
  fft16_reg(v);
}

// ---------------------------------------------------------------------------
// FFT pass 1 + tiled transpose. Natural-lane coalesced loads; Zt storage row
// rr holds spectral pi(rr) = (rr&960)|brev6(rr&63) (involution).
// ---------------------------------------------------------------------------
__global__ __launch_bounds__(512, 2)
void fft_rows_t_kernel(const float* __restrict__ pred, const float* __restrict__ targ,
                       float2* __restrict__ Zt){
  __shared__ float2 tile[8][64][9];
  const int tid = threadIdx.x;
  const int lane = tid & 63;
  const int w = tid >> 6;
  const int y0 = blockIdx.x << 3;
  const size_t ibase = ((size_t)blockIdx.y * HW + (y0 + w)) * HW;
  const int rb = __brev(lane) >> 26;           // logical lane for the FFT
  const float4* p4 = (const float4*)(pred + ibase);
  const float4* t4 = (const float4*)(targ + ibase);
  float2 v[16];
  #pragma unroll
  for (int m = 0; m < 4; m++){
    float4 a = p4[4*lane + m];                 // natural order: x[16*lane + 4m ..]
    float4 b = t4[4*lane + m];
    v[4*m+0] = make_float2(a.x, b.x);
    v[4*m+1] = make_float2(a.y, b.y);
    v[4*m+2] = make_float2(a.z, b.z);
    v[4*m+3] = make_float2(a.w, b.w);
  }
  fft1024_wave(v, rb);
  float2* zb = Zt + (size_t)blockIdx.y * HW * HW + (size_t)blockIdx.x * 8192;
  const int yl = tid & 7, kl = tid >> 3;
  #pragma unroll
  for (int jb = 0; jb < 2; jb++){
    __syncthreads();
    #pragma unroll
    for (int jj = 0; jj < 8; jj++) tile[jj][lane][w] = v[8*jb + jj];
    __syncthreads();
    #pragma unroll
    for (int jj = 0; jj < 8; jj++){
      int k = ((jb << 3) + jj) * 64 + kl;      // storage row; spectral = pi(row)
      zb[k * 8 + yl] = tile[jj][kl][yl];       // contiguous across the block
    }
  }
}

// ---------------------------------------------------------------------------
// FFT pass 2 + reduce + FUSED finalize (R25): last-block-done trick.
// All threads stay live through the barriers (no early returns).
// ---------------------------------------------------------------------------
__device__ __forceinline__ void freq_contrib(float2 Zk, float2 Zm, int k1, int k2,
                                             float& ms, float& ps){
  int di = k1 - 512, dj = k2 - 512;
  if (di*di + dj*dj < 94372) return;         // dist > 307.2  <=>  r2 >= 94372
  float pr = 0.5f*(Zk.x + Zm.x);
  float pi = 0.5f*(Zk.y - Zm.y);
  float tr = 0.5f*(Zk.y + Zm.y);
  float ti = 0.5f*(Zm.x - Zk.x);
  float p2 = pr*pr + pi*pi;
  float t2 = tr*tr + ti*ti;
  ms += p2 + t2 - 2.f*fsqrt(p2*t2);
  float re = pr*tr + pi*ti;
  float im = pi*tr - pr*ti;
  float pd = fast_atan2_abs(fabsf(im), re);  // squared below; sign irrelevant
  ps += pd*pd;
}

__global__ __launch_bounds__(256, 2)
void fft_cols2_kernel(const float2* __restrict__ Z, double* __restrict__ acc,
                      unsigned* __restrict__ done, float* __restrict__ out){
  __shared__ float2 ex[4][1024];            // per-wave natural-order spectrum
  __shared__ int is_last;
  const int tid = threadIdx.x;
  const int lane = tid & 63;
  const int w = tid >> 6;                   // 0..3
  const int p = 2 * blockIdx.x + (w >> 1);  // pair index, 0..512 valid
  const bool valid = (p <= 512);
  const int r_spec = (w & 1) ? ((1024 - p) & 1023) : p;   // spectral row (k1)
  const int rr = (r_spec & 0x3C0) | (__brev(r_spec & 63) >> 26); // Zt storage row
  const float2* base = Z + (size_t)blockIdx.y * HW * HW;
  const int bl = __brev(lane) >> 26;        // logical lane for the FFT

  float2 v[16];
  if (valid){
    const float4* f4 = (const float4*)base;
    #pragma unroll
    for (int s = 0; s < 2; s++){
      size_t o = (size_t)(2*lane + s) * 4096 + (size_t)rr * 4;  // float4 units
      #pragma unroll
      for (int q = 0; q < 4; q++){
        float4 x = f4[o + q];
        v[8*s + 2*q]     = make_float2(x.x, x.y);
        v[8*s + 2*q + 1] = make_float2(x.z, x.w);
      }
    }
    fft1024_wave(v, bl);
    #pragma unroll
    for (int j = 0; j < 16; j++) ex[w][bl + (j << 6)] = v[j];   // natural order
  }
  __syncthreads();

  const bool self = (p == 0) || (p == 512);
  if (valid && !((w & 1) && self)){
    const float2* pb = ex[w ^ 1];           // partner spectrum, natural order
    float ms = 0.f, ps = 0.f;
    #pragma unroll
    for (int j = 0; j < 16; j++){
      int k = bl + (j << 6);                // this value's spectral index k2
      float2 zm = pb[(1024 - k) & 1023];    // Z_partner(-k)
      freq_contrib(v[j], zm, k, r_spec, ms, ps);
    }
    #pragma unroll
    for (int o = 32; o > 0; o >>= 1){
      ms += __shfl_down(ms, o, 64);
      ps += __shfl_down(ps, o, 64);
    }
    if (lane == 0){
      int slot = (r_spec + blockIdx.y * 11) & (NSLOT - 1);
      atomicAdd(&acc[3*NSLOT + slot], (double)ms);
      atomicAdd(&acc[4*NSLOT + slot], (double)ps);
    }
  }

  // last-block finalize: device-scope counter; all threads alive for barriers.
  __syncthreads();
  if (tid == 0){
    __threadfence();
    is_last = (atomicAdd(done, 1u) == COLS_NBLK - 1u) ? 1 : 0;
  }
  __syncthreads();
  if (is_last && tid < 64){
    const volatile double* va = acc;        // atomics landed in L2; L1 cold here
    double vv[5];
    #pragma unroll
    for (int s = 0; s < 5; s++) vv[s] = va[s*NSLOT + tid];
    #pragma unroll
    for (int o = 32; o > 0; o >>= 1)
      #pragma unroll
      for (int s = 0; s < 5; s++) vv[s] += __shfl_down(vv[s], o, 64);
    if (tid == 0){
      const double inv = 1.0 / 8388608.0;    // mean over 8*1024*1024
      double grad   = vv[0] * inv / 3.0;     // / len(bms)
      double smooth = vv[1] * inv;
      double slope  = vv[2] * inv;
      double freq   = (vv[3] + 2.0 * vv[4]) * inv;
      double total  = 2.0*grad + 1.5*freq + 3.0*smooth + 2.0*slope;
      out[0] = (float)total;
      out[1] = (float)grad;
      out[2] = (float)freq;
      out[3] = (float)smooth;
      out[4] = (float)slope;
    }
  }
}

extern "C" void kernel_launch(void* const* d_in, const int* in_sizes, int n_in,
                              void* d_out, int out_size, void* d_ws, size_t ws_size,
                              hipStream_t stream){
  const float* pred = (const float*)d_in[0];
  const float* targ = (const float*)d_in[1];
  const float* mask = (const float*)d_in[2];
  double* acc    = (double*)d_ws;                       // [0, 2560)
  unsigned* done = (unsigned*)((char*)d_ws + 2560);     // [2560, 2564)
  float2* Z      = (float2*)((char*)d_ws + 8192);       // 8 x 8 MiB fp32 images

  // zero acc + done in one async memset (graph-capture-safe)
  hipMemsetAsync(d_ws, 0, 4096, stream);
  spatial_kernel<<<dim3(32, 32, 8), 256, 0, stream>>>(pred, targ, mask, acc);
  fft_rows_t_kernel<<<dim3(128, 8), 512, 0, stream>>>(pred, targ, Z);
  fft_cols2_kernel<<<dim3(257, 8), 256, 0, stream>>>(Z, acc, done, (float*)d_out);
}

// Round 14
// 228.171 us; speedup vs baseline: 1.1708x; 1.1708x over previous
//
#include <hip/hip_runtime.h>

#define HW 1024
#define TWO_PI_F 6.28318530717958647692f
#define NSLOT 64   // atomic spreading: 64 slots per accumulator, 5 accumulators

typedef float v2f __attribute__((ext_vector_type(2)));
typedef int   i2v __attribute__((ext_vector_type(2)));

__device__ __forceinline__ v2f mkv2(float a, float b){ v2f r; r.x = a; r.y = b; return r; }
__device__ __forceinline__ v2f v2s(float s){ v2f r; r.x = s; r.y = s; return r; }

__device__ __forceinline__ float2 cmulf(float2 a, float2 b){
  return make_float2(a.x*b.x - a.y*b.y, a.x*b.y + a.y*b.x);
}
__device__ __forceinline__ float fsqrt(float x){ return __builtin_amdgcn_sqrtf(x); }

// fast |atan2|: caller passes ay = |y| >= 0. Saves the final sign-select.
__device__ __forceinline__ float fast_atan2_abs(float ay, float x){
  float ax = fabsf(x);
  float mx = fmaxf(ax, ay), mn = fminf(ax, ay);
  float a  = mn * __builtin_amdgcn_rcpf(fmaxf(mx, 1e-37f));
  float s  = a * a;
  float r  = ((((0.0208351f*s - 0.085133f)*s + 0.180141f)*s - 0.3302995f)*s
              + 0.999866f) * a;
  r = (ay > ax) ? 1.57079632679f - r : r;
  return (x < 0.f) ? 3.14159265359f - r : r;
}

// 256-thread block reduction (4 waves of 64), float
__device__ __forceinline__ float block_reduce_add_f(float v, float* sc){
  int tid = threadIdx.x;
  #pragma unroll
  for (int o = 32; o > 0; o >>= 1) v += __shfl_down(v, o, 64);
  __syncthreads();
  if ((tid & 63) == 0) sc[tid >> 6] = v;
  __syncthreads();
  return sc[0] + sc[1] + sc[2] + sc[3];
}

// merged setup: zero accumulators + twiddle table (one launch).
// R26: restored — R24/R25 measured in-kernel twiddle gen (sincosf +9us;
// fused finalize +35us) strictly worse than this 1-2us helper dispatch.
__global__ void setup_kernel(double* acc, float2* twg){
  int i = threadIdx.x + blockIdx.x * 256;   // grid 2 x 256 -> 0..511
  if (i < 5 * NSLOT) acc[i] = 0.0;
  if (i < 512){
    float s, c; sincosf(-TWO_PI_F * (float)i * (1.f/1024.f), &s, &c);
    twg[i] = make_float2(c, s);
  }
}

// ---------------------------------------------------------------------------
// Spatial half (R17/R21-verified body; one dispatch per R24 measurement).
// ---------------------------------------------------------------------------
__global__ __launch_bounds__(256, 4)
void spatial_kernel(const float* __restrict__ pred, const float* __restrict__ targ,
                    const float* __restrict__ mask, double* __restrict__ acc){
  __shared__ v2f spt[36*44];               // (pred, targ) halo tile, stride 44
  __shared__ v2f pmt[34*35];               // union: smkf float[38*41] / (pmag,tmag)
  __shared__ unsigned long long mrow[38];
  __shared__ float sc[4];
  float* const smkf = (float*)pmt;         // 1558 floats = 6232 B <= 9520 B

  const int tid = threadIdx.x;
  const int x0 = blockIdx.x << 5, y0 = blockIdx.y << 5;
  const int z = blockIdx.z;
  const size_t ib = (size_t)z * ((size_t)HW * HW);
  const bool interior = ((unsigned)(blockIdx.x - 1) < 30u) &&
                        ((unsigned)(blockIdx.y - 1) < 30u);

  if (interior){
    const float* pb = pred + ib;
    const float* tb = targ + ib;
    for (int i = tid; i < 360; i += 256){        // 36 rows x 10 float4 (40 cols)
      int a = i / 10, b = i % 10;
      size_t off = (size_t)(y0 - 2 + a) * HW + (x0 - 4 + 4*b);
      float4 pv = *(const float4*)(pb + off);
      float4 tv = *(const float4*)(tb + off);
      int o = a*44 + 4*b;
      spt[o+0] = mkv2(pv.x, tv.x);
      spt[o+1] = mkv2(pv.y, tv.y);
      spt[o+2] = mkv2(pv.z, tv.z);
      spt[o+3] = mkv2(pv.w, tv.w);
    }
    const float* mb = mask + ib;
    for (int i = tid; i < 380; i += 256){        // 38 rows x 10 float4
      int a = i / 10, b = i % 10;
      size_t off = (size_t)(y0 - 3 + a) * HW + (x0 - 4 + 4*b);
      float4 v = *(const float4*)(mb + off);
      int o = a*41 + 4*b;
      smkf[o]=v.x; smkf[o+1]=v.y; smkf[o+2]=v.z; smkf[o+3]=v.w;
    }
  } else {
    for (int i = tid; i < 1296; i += 256){
      int a = i / 36, b = i % 36;
      int gy = y0 - 2 + a, gx = x0 - 2 + b;
      float pv = 0.f, tv = 0.f;
      if ((unsigned)gy < HW && (unsigned)gx < HW){
        size_t idx = ib + (size_t)gy * HW + gx;
        pv = pred[idx]; tv = targ[idx];
      }
      spt[a*44 + b + 2] = mkv2(pv, tv);
    }
    for (int i = tid; i < 1444; i += 256){
      int a = i / 38, b = i % 38;
      int gy = y0 - 3 + a, gx = x0 - 3 + b;
      float v = 0.f;
      if ((unsigned)gy < HW && (unsigned)gx < HW) v = mask[ib + (size_t)gy * HW + gx];
      smkf[a*41 + b + 1] = v;
    }
  }
  __syncthreads();

  // wave-parallel mask rows via ballot (lanes 0..37 active per row)
  {
    const int wv = tid >> 6, lane = tid & 63;
    for (int r = wv; r < 38; r += 4){
      float val = (lane < 38) ? smkf[r*41 + 1 + lane] : 0.f;
      unsigned long long m = __ballot(val > 0.5f);
      if (lane == 0) mrow[r] = m;
    }
  }
  __syncthreads();                              // smkf reads done; pmt reuse ok

  if (interior){
    for (int i = tid; i < 1156; i += 256){      // no bounds checks: always in-range
      int iy = i / 34, ix = i % 34;
      int o = iy*44 + ix + 2;
      v2f a00=spt[o],    a01=spt[o+1],  a02=spt[o+2];
      v2f a10=spt[o+44],                a12=spt[o+46];
      v2f a20=spt[o+88], a21=spt[o+89], a22=spt[o+90];
      v2f gx = (a02 + v2s(2.f)*a12 + a22) - (a00 + v2s(2.f)*a10 + a20);
      v2f gy = (a20 + v2s(2.f)*a21 + a22) - (a00 + v2s(2.f)*a01 + a02);
      v2f m2 = gx*gx + gy*gy + v2s(1e-8f);
      pmt[iy*35+ix] = mkv2(fsqrt(m2.x), fsqrt(m2.y));
    }
  } else {
    for (int i = tid; i < 1156; i += 256){
      int iy = i / 34, ix = i % 34;
      int gy = y0 - 1 + iy, gx = x0 - 1 + ix;
      v2f out = v2s(0.f);
      if ((unsigned)gy < HW && (unsigned)gx < HW){
        int o = iy*44 + ix + 2;
        v2f a00=spt[o],    a01=spt[o+1],  a02=spt[o+2];
        v2f a10=spt[o+44],                a12=spt[o+46];
        v2f a20=spt[o+88], a21=spt[o+89], a22=spt[o+90];
        v2f gxv = (a02 + v2s(2.f)*a12 + a22) - (a00 + v2s(2.f)*a10 + a20);
        v2f gyv = (a20 + v2s(2.f)*a21 + a22) - (a00 + v2s(2.f)*a01 + a02);
        v2f m2 = gxv*gxv + gyv*gyv + v2s(1e-8f);
        out = mkv2(fsqrt(m2.x), fsqrt(m2.y));
      }
      pmt[iy*35+ix] = out;
    }
  }
  __syncthreads();

  const int ty = tid >> 5, tx = tid & 31;
  const int r0 = ty << 2;

  // packed counts: cp[j] = c1 | c2<<8 | c3<<16 (vertical sums can't carry)
  int cp[10];
  #pragma unroll
  for (int j = 0; j < 10; j++){
    unsigned w = (unsigned)(mrow[r0 + j] >> tx);
    int c3 = __popc(w & 0x7Fu);
    int c2 = __popc((w >> 1) & 0x1Fu);
    int c1 = __popc((w >> 2) & 0x7u);
    cp[j] = c1 | (c2 << 8) | (c3 << 16);
  }

  v2f PQ[3][3], AB[3][3];
  #pragma unroll
  for (int rr = 0; rr < 2; rr++)
    #pragma unroll
    for (int cc = 0; cc < 3; cc++){
      PQ[rr][cc] = spt[(r0+1+rr)*44 + tx+3+cc];
      AB[rr][cc] = pmt[(r0+rr)*35 + tx+cc];
    }

  // per-row rolling state: slot r <-> PQ row (r0+1+r) / AB row (r0+r)
  v2f wR[6], wA[6];      // (1,2,1)-weighted row sums (sobel-y / slope-y)
  float uR[6], qR[6];    // plain and squared row sums of pred (smooth)
  #pragma unroll
  for (int r = 0; r < 2; r++){
    wR[r] = PQ[r][0] + v2s(2.f)*PQ[r][1] + PQ[r][2];
    float p0 = PQ[r][0].x, p1 = PQ[r][1].x, p2 = PQ[r][2].x;
    uR[r] = p0 + p1 + p2;
    qR[r] = fmaf(p0, p0, fmaf(p1, p1, p2*p2));
    wA[r] = AB[r][0] + v2s(2.f)*AB[r][1] + AB[r][2];
  }

  float accg = 0.f, accs = 0.f, accl = 0.f;
  #pragma unroll
  for (int k = 0; k < 4; k++){
    #pragma unroll
    for (int cc = 0; cc < 3; cc++){
      PQ[2][cc] = spt[(r0+k+3)*44 + tx+3+cc];
      AB[2][cc] = pmt[(r0+k+2)*35 + tx+cc];
    }
    {
      wR[k+2] = PQ[2][0] + v2s(2.f)*PQ[2][1] + PQ[2][2];
      float p0 = PQ[2][0].x, p1 = PQ[2][1].x, p2 = PQ[2][2].x;
      uR[k+2] = p0 + p1 + p2;
      qR[k+2] = fmaf(p0, p0, fmaf(p1, p1, p2*p2));
      wA[k+2] = AB[2][0] + v2s(2.f)*AB[2][1] + AB[2][2];
    }

    v2f gxv = (PQ[0][2] + v2s(2.f)*PQ[1][2] + PQ[2][2]) - (PQ[0][0] + v2s(2.f)*PQ[1][0] + PQ[2][0]);
    v2f gyv = wR[k+2] - wR[k];
    v2f cvv = v2s(4.f)*PQ[1][1] - PQ[0][1] - PQ[1][0] - PQ[1][2] - PQ[2][1];

    float sd = fabsf(AB[1][1].x - AB[1][1].y);
    float x1 = gxv.x + 1e-8f, y1 = gyv.x;
    float x2 = gxv.y + 1e-8f, y2 = gyv.y;
    float dd = fast_atan2_abs(fabsf(y1*x2 - x1*y2), x1*x2 + y1*y2);
    float cd = fabsf(cvv.x - cvv.y);

    int s1p = cp[k+2] + cp[k+3] + cp[k+4];
    int s2p = s1p + cp[k+1] + cp[k+5];
    int s3p = s2p + cp[k]   + cp[k+6];
    int s1 = s1p & 0xFF;
    int s2 = (s2p >> 8) & 0xFF;
    int s3 = s3p >> 16;
    float w1 = ((unsigned)(s1 - 1) <  8u) ? 1.f : 0.f;
    float w2 = ((unsigned)(s2 - 1) < 24u) ? 1.f : 0.f;
    float w3 = ((unsigned)(s3 - 1) < 48u) ? 1.f : 0.f;
    float wa = fmaf(0.5f, w2 + w3, w1);

    accg = fmaf(wa, sd + dd + 2.f*cd, accg);

    float s9 = uR[k] + uR[k+1] + uR[k+2];
    float s9q = qR[k] + qR[k+1] + qR[k+2];
    float lm = s9 * (1.f/9.f), lq = s9q * (1.f/9.f);
    accs = fmaf(fsqrt(fmaxf(lq - lm*lm, 1e-8f)), w1, accs);

    v2f px = (AB[0][2] + v2s(2.f)*AB[1][2] + AB[2][2]) - (AB[0][0] + v2s(2.f)*AB[1][0] + AB[2][0]);
    v2f py = wA[k+2] - wA[k];
    v2f ch2 = px*px + py*py + v2s(1e-8f);
    accl = fmaf(fabsf(fsqrt(ch2.x) - fsqrt(ch2.y)), w1, accl);

    if (k < 3){
      #pragma unroll
      for (int cc = 0; cc < 3; cc++){
        PQ[0][cc] = PQ[1][cc]; PQ[1][cc] = PQ[2][cc];
        AB[0][cc] = AB[1][cc]; AB[1][cc] = AB[2][cc];
      }
    }
  }

  float g  = block_reduce_add_f(accg, sc);
  float sm = block_reduce_add_f(accs, sc);
  float sl = block_reduce_add_f(accl, sc);
  if (tid == 0){
    int slot = (blockIdx.x + blockIdx.y * 7 + z * 13) & (NSLOT - 1);
    atomicAdd(&acc[0*NSLOT + slot], (double)g);
    atomicAdd(&acc[1*NSLOT + slot], (double)sm);
    atomicAdd(&acc[2*NSLOT + slot], (double)sl);
  }
}

// ---------------------------------------------------------------------------
// ALL-VALU lane exchanges (R20-verified primitives).
// ---------------------------------------------------------------------------
template<int CTRL>
__device__ __forceinline__ float xordpp(float x){
  int xi = __float_as_int(x);
  return __int_as_float(__builtin_amdgcn_update_dpp(xi, xi, CTRL, 0xF, 0xF, true));
}
__device__ __forceinline__ float xor4v(float x){
  int xi = __float_as_int(x);
  int t1 = __builtin_amdgcn_update_dpp(xi, xi, 0x104, 0xF, 0x5, false); // SHL4 -> banks 0,2
  int t2 = __builtin_amdgcn_update_dpp(t1, xi, 0x114, 0xF, 0xA, false); // SHR4 -> banks 1,3
  return __int_as_float(t2);
}

#define FC 0.70710678118654752f
#define FC1 0.92387953251128676f
#define FS1 0.38268343236508977f

__device__ __forceinline__ void bfly(float2& a, float2& b){
  float tx = b.x, ty = b.y;
  b.x = a.x - tx; b.y = a.y - ty;
  a.x += tx;      a.y += ty;
}
__device__ __forceinline__ void cmul_c(float2& b, float wr, float wi){
  float tx = wr*b.x - wi*b.y, ty = wr*b.y + wi*b.x;
  b.x = tx; b.y = ty;
}
__device__ __forceinline__ void rotmi(float2& b){   // b *= -i
  float t = b.x; b.x = b.y; b.y = -t;
}

__device__ __forceinline__ void fft16_reg(float2* v){
  float2 y[16];
  y[0]=v[0];  y[1]=v[8];  y[2]=v[4];  y[3]=v[12];
  y[4]=v[2];  y[5]=v[10]; y[6]=v[6];  y[7]=v[14];
  y[8]=v[1];  y[9]=v[9];  y[10]=v[5]; y[11]=v[13];
  y[12]=v[3]; y[13]=v[11];y[14]=v[7]; y[15]=v[15];
  #pragma unroll
  for (int g = 0; g < 8; g++) bfly(y[2*g], y[2*g+1]);
  #pragma unroll
  for (int g = 0; g < 4; g++){
    int b = 4*g;
    bfly(y[b], y[b+2]);
    rotmi(y[b+3]); bfly(y[b+1], y[b+3]);
  }
  #pragma unroll
  for (int g = 0; g < 2; g++){
    int b = 8*g;
    bfly(y[b], y[b+4]);
    cmul_c(y[b+5],  FC, -FC); bfly(y[b+1], y[b+5]);
    rotmi(y[b+6]);            bfly(y[b+2], y[b+6]);
    cmul_c(y[b+7], -FC, -FC); bfly(y[b+3], y[b+7]);
  }
  bfly(y[0], y[8]);
  cmul_c(y[9],   FC1, -FS1); bfly(y[1], y[9]);
  cmul_c(y[10],  FC,  -FC);  bfly(y[2], y[10]);
  cmul_c(y[11],  FS1, -FC1); bfly(y[3], y[11]);
  rotmi(y[12]);              bfly(y[4], y[12]);
  cmul_c(y[13], -FS1, -FC1); bfly(y[5], y[13]);
  cmul_c(y[14], -FC,  -FC);  bfly(y[6], y[14]);
  cmul_c(y[15], -FC1, -FS1); bfly(y[7], y[15]);
  #pragma unroll
  for (int j = 0; j < 16; j++) v[j] = y[j];
}

// ---------------------------------------------------------------------------
// Natural-lane DIT (R22-verified): logical lane L = brev6(p); natural input
// order; six verified exchange primitives in reversed order; output
// X[brev6(p)+64j]. Twiddles from table (R26: measured fastest variant).
// ---------------------------------------------------------------------------
__device__ __forceinline__ void fft1024_wave(float2* v, int lane /*logical L*/,
                                             const float2* __restrict__ twg){
  const float2 tw1 = twg[(lane & 1) << 8];
  const float2 tw2 = twg[(lane & 3) << 7];
  const float2 tw3 = twg[(lane & 7) << 6];
  const float2 tw4 = twg[(lane & 15) << 5];
  const float2 tw5 = twg[(lane & 31) << 4];
  const float2 wq  = twg[lane];

  // stage 0 (logical h=1 -> physical 32): permlane32 fused, w=1
  {
    const float sgn = (lane & 1) ? -1.f : 1.f;
    #pragma unroll
    for (int j = 0; j < 16; j++){
      i2v px = __builtin_amdgcn_permlane32_swap(__float_as_int(v[j].x), __float_as_int(v[j].x), false, false);
      i2v py = __builtin_amdgcn_permlane32_swap(__float_as_int(v[j].y), __float_as_int(v[j].y), false, false);
      v[j].x = fmaf(sgn, __int_as_float(px.y), __int_as_float(px.x));
      v[j].y = fmaf(sgn, __int_as_float(py.y), __int_as_float(py.x));
    }
  }
  // stage 1 (logical h=2 -> physical 16): permlane16 fused
  {
    const bool up = (lane & 2) != 0;
    const float ewx = up ? tw1.x : 1.f, ewy = up ? tw1.y : 0.f;
    const float sgn = up ? -1.f : 1.f;
    #pragma unroll
    for (int j = 0; j < 16; j++){
      float tx = ewx*v[j].x - ewy*v[j].y;
      float ty = ewx*v[j].y + ewy*v[j].x;
      i2v px = __builtin_amdgcn_permlane16_swap(__float_as_int(tx), __float_as_int(tx), false, false);
      i2v py = __builtin_amdgcn_permlane16_swap(__float_as_int(ty), __float_as_int(ty), false, false);
      v[j].x = fmaf(sgn, __int_as_float(px.y), __int_as_float(px.x));
      v[j].y = fmaf(sgn, __int_as_float(py.y), __int_as_float(py.x));
    }
  }
  // stage 2 (logical h=4 -> physical 8): ROW_ROR:8
  {
    const bool up = (lane & 4) != 0;
    const float ewx = up ? tw2.x : 1.f, ewy = up ? tw2.y : 0.f;
    const float sgn = up ? -1.f : 1.f;
    #pragma unroll
    for (int j = 0; j < 16; j++){
      float tx = ewx*v[j].x - ewy*v[j].y;
      float ty = ewx*v[j].y + ewy*v[j].x;
      v[j].x = fmaf(sgn, tx, xordpp<0x128>(tx));
      v[j].y = fmaf(sgn, ty, xordpp<0x128>(ty));
    }
  }
  // stage 3 (logical h=8 -> physical 4): bank-masked DPP pair
  {
    const bool up = (lane & 8) != 0;
    const float ewx = up ? tw3.x : 1.f, ewy = up ? tw3.y : 0.f;
    const float sgn = up ? -1.f : 1.f;
    #pragma unroll
    for (int j = 0; j < 16; j++){
      float tx = ewx*v[j].x - ewy*v[j].y;
      float ty = ewx*v[j].y + ewy*v[j].x;
      v[j].x = fmaf(sgn, tx, xor4v(tx));
      v[j].y = fmaf(sgn, ty, xor4v(ty));
    }
  }
  // stage 4 (logical h=16 -> physical 2): quad_perm xor2
  {
    const bool up = (lane & 16) != 0;
    const float ewx = up ? tw4.x : 1.f, ewy = up ? tw4.y : 0.f;
    const float sgn = up ? -1.f : 1.f;
    #pragma unroll
    for (int j = 0; j < 16; j++){
      float tx = ewx*v[j].x - ewy*v[j].y;
      float ty = ewx*v[j].y + ewy*v[j].x;
      v[j].x = fmaf(sgn, tx, xordpp<0x4E>(tx));
      v[j].y = fmaf(sgn, ty, xordpp<0x4E>(ty));
    }
  }
  // stage 5 (logical h=32 -> physical 1): quad_perm xor1
  {
    const bool up = (lane & 32) != 0;
    const float ewx = up ? tw5.x : 1.f, ewy = up ? tw5.y : 0.f;
    const float sgn = up ? -1.f : 1.f;
    #pragma unroll
    for (int j = 0; j < 16; j++){
      float tx = ewx*v[j].x - ewy*v[j].y;
      float ty = ewx*v[j].y + ewy*v[j].x;
      v[j].x = fmaf(sgn, tx, xordpp<0xB1>(tx));
      v[j].y = fmaf(sgn, ty, xordpp<0xB1>(ty));
    }
  }
  // per-slot twiddle: v[j] *= wq^j; log-depth powers
  float2 w2 = cmulf(wq, wq);
  float2 w3 = cmulf(w2, wq);
  float2 w4 = cmulf(w2, w2);
  float2 w5 = cmulf(w3, w2);
  float2 w6 = cmulf(w3, w3);
  float2 w7 = cmulf(w4, w3);
  float2 w8 = cmulf(w4, w4);
  v[1]  = cmulf(v[1],  wq);
  v[2]  = cmulf(v[2],  w2);
  v[3]  = cmulf(v[3],  w3);
  v[4]  = cmulf(v[4],  w4);
  v[5]  = cmulf(v[5],  w5);
  v[6]  = cmulf(v[6],  w6);
  v[7]  = cmulf(v[7],  w7);
  v[8]  = cmulf(v[8],  w8);
  v[9]  = cmulf(cmulf(v[9],  w8), wq);
  v[10] = cmulf(cmulf(v[10], w8), w2);
  v[11] = cmulf(cmulf(v[11], w8), w3);
  v[12] = cmulf(cmulf(v[12], w8), w4);
  v[13] = cmulf(cmulf(v[13], w8), w5);
  v[14] = cmulf(cmulf(v[14], w8), w6);
  v[15] = cmulf(cmulf(v[15], w8), w7);
  fft16_reg(v);
}

// ---------------------------------------------------------------------------
// FFT pass 1 + tiled transpose. Natural-lane coalesced loads; Zt storage row
// rr holds spectral pi(rr) = (rr&960)|brev6(rr&63) (involution).
// ---------------------------------------------------------------------------
__global__ __launch_bounds__(512, 2)
void fft_rows_t_kernel(const float* __restrict__ pred, const float* __restrict__ targ,
                       float2* __restrict__ Zt, const float2* __restrict__ twg){
  __shared__ float2 tile[8][64][9];
  const int tid = threadIdx.x;
  const int lane = tid & 63;
  const int w = tid >> 6;
  const int y0 = blockIdx.x << 3;
  const size_t ibase = ((size_t)blockIdx.y * HW + (y0 + w)) * HW;
  const int rb = __brev(lane) >> 26;           // logical lane for the FFT
  const float4* p4 = (const float4*)(pred + ibase);
  const float4* t4 = (const float4*)(targ + ibase);
  float2 v[16];
  #pragma unroll
  for (int m = 0; m < 4; m++){
    float4 a = p4[4*lane + m];                 // natural order: x[16*lane + 4m ..]
    float4 b = t4[4*lane + m];
    v[4*m+0] = make_float2(a.x, b.x);
    v[4*m+1] = make_float2(a.y, b.y);
    v[4*m+2] = make_float2(a.z, b.z);
    v[4*m+3] = make_float2(a.w, b.w);
  }
  fft1024_wave(v, rb, twg);
  float2* zb = Zt + (size_t)blockIdx.y * HW * HW + (size_t)blockIdx.x * 8192;
  const int yl = tid & 7, kl = tid >> 3;
  #pragma unroll
  for (int jb = 0; jb < 2; jb++){
    __syncthreads();
    #pragma unroll
    for (int jj = 0; jj < 8; jj++) tile[jj][lane][w] = v[8*jb + jj];
    __syncthreads();
    #pragma unroll
    for (int jj = 0; jj < 8; jj++){
      int k = ((jb << 3) + jj) * 64 + kl;      // storage row; spectral = pi(row)
      zb[k * 8 + yl] = tile[jj][kl][yl];       // contiguous across the block
    }
  }
}

// ---------------------------------------------------------------------------
// FFT pass 2 + reduce (R23-verified structure: early returns, LDS exactly
// 32768 B -> 5 blocks/CU; separate finalize dispatch).
// ---------------------------------------------------------------------------
__device__ __forceinline__ void freq_contrib(float2 Zk, float2 Zm, int k1, int k2,
                                             float& ms, float& ps){
  int di = k1 - 512, dj = k2 - 512;
  if (di*di + dj*dj < 94372) return;         // dist > 307.2  <=>  r2 >= 94372
  float pr = 0.5f*(Zk.x + Zm.x);
  float pi = 0.5f*(Zk.y - Zm.y);
  float tr = 0.5f*(Zk.y + Zm.y);
  float ti = 0.5f*(Zm.x - Zk.x);
  float p2 = pr*pr + pi*pi;
  float t2 = tr*tr + ti*ti;
  ms += p2 + t2 - 2.f*fsqrt(p2*t2);
  float re = pr*tr + pi*ti;
  float im = pi*tr - pr*ti;
  float pd = fast_atan2_abs(fabsf(im), re);  // squared below; sign irrelevant
  ps += pd*pd;
}

__global__ __launch_bounds__(256, 2)
void fft_cols2_kernel(const float2* __restrict__ Z, const float2* __restrict__ twg,
                      double* __restrict__ acc){
  __shared__ float2 ex[4][1024];            // per-wave natural-order spectrum
  const int lane = threadIdx.x & 63;
  const int w = threadIdx.x >> 6;           // 0..3
  const int p = 2 * blockIdx.x + (w >> 1);  // pair index, 0..512 valid
  const bool valid = (p <= 512);
  const int r_spec = (w & 1) ? ((1024 - p) & 1023) : p;   // spectral row (k1)
  const int rr = (r_spec & 0x3C0) | (__brev(r_spec & 63) >> 26); // Zt storage row
  const float2* base = Z + (size_t)blockIdx.y * HW * HW;
  const int bl = __brev(lane) >> 26;        // logical lane for the FFT

  float2 v[16];
  if (valid){
    const float4* f4 = (const float4*)base;
    #pragma unroll
    for (int s = 0; s < 2; s++){
      size_t o = (size_t)(2*lane + s) * 4096 + (size_t)rr * 4;  // float4 units
      #pragma unroll
      for (int q = 0; q < 4; q++){
        float4 x = f4[o + q];
        v[8*s + 2*q]     = make_float2(x.x, x.y);
        v[8*s + 2*q + 1] = make_float2(x.z, x.w);
      }
    }
    fft1024_wave(v, bl, twg);
    #pragma unroll
    for (int j = 0; j < 16; j++) ex[w][bl + (j << 6)] = v[j];   // natural order
  }
  __syncthreads();
  if (!valid) return;
  const bool self = (p == 0) || (p == 512);
  if ((w & 1) && self) return;              // duplicate row: LDS written, no contribs

  const float2* pb = ex[w ^ 1];             // partner spectrum, natural order
  float ms = 0.f, ps = 0.f;
  #pragma unroll
  for (int j = 0; j < 16; j++){
    int k = bl + (j << 6);                  // this value's spectral index k2
    float2 zm = pb[(1024 - k) & 1023];      // Z_partner(-k)
    freq_contrib(v[j], zm, k, r_spec, ms, ps);
  }
  #pragma unroll
  for (int o = 32; o > 0; o >>= 1){
    ms += __shfl_down(ms, o, 64);
    ps += __shfl_down(ps, o, 64);
  }
  if (lane == 0){
    int slot = (r_spec + blockIdx.y * 11) & (NSLOT - 1);
    atomicAdd(&acc[3*NSLOT + slot], (double)ms);
    atomicAdd(&acc[4*NSLOT + slot], (double)ps);
  }
}

// ---------------------------------------------------------------------------
__global__ void finalize_kernel(const double* __restrict__ acc, float* __restrict__ out){
  const int t = threadIdx.x;   // 64 threads
  double v[5];
  #pragma unroll
  for (int s = 0; s < 5; s++) v[s] = acc[s*NSLOT + t];
  #pragma unroll
  for (int o = 32; o > 0; o >>= 1)
    #pragma unroll
    for (int s = 0; s < 5; s++) v[s] += __shfl_down(v[s], o, 64);
  if (t == 0){
    const double inv = 1.0 / 8388608.0;      // mean over 8*1024*1024
    double grad   = v[0] * inv / 3.0;        // / len(bms)
    double smooth = v[1] * inv;
    double slope  = v[2] * inv;
    double freq   = (v[3] + 2.0 * v[4]) * inv;
    double total  = 2.0*grad + 1.5*freq + 3.0*smooth + 2.0*slope;
    out[0] = (float)total;
    out[1] = (float)grad;
    out[2] = (float)freq;
    out[3] = (float)smooth;
    out[4] = (float)slope;
  }
}

extern "C" void kernel_launch(void* const* d_in, const int* in_sizes, int n_in,
                              void* d_out, int out_size, void* d_ws, size_t ws_size,
                              hipStream_t stream){
  const float* pred = (const float*)d_in[0];
  const float* targ = (const float*)d_in[1];
  const float* mask = (const float*)d_in[2];
  double* acc  = (double*)d_ws;                         // [0, 2560)
  float2* twg  = (float2*)((char*)d_ws + 4096);         // [4096, 8192)
  float2* Z    = (float2*)((char*)d_ws + 8192);         // 8 x 8 MiB fp32 images

  setup_kernel<<<2, 256, 0, stream>>>(acc, twg);
  spatial_kernel<<<dim3(32, 32, 8), 256, 0, stream>>>(pred, targ, mask, acc);
  fft_rows_t_kernel<<<dim3(128, 8), 512, 0, stream>>>(pred, targ, Z, twg);
  fft_cols2_kernel<<<dim3(257, 8), 256, 0, stream>>>(Z, twg, acc);
  finalize_kernel<<<1, 64, 0, stream>>>(acc, (float*)d_out);
}

// Round 15
// 226.660 us; speedup vs baseline: 1.1786x; 1.0067x over previous
//
#include <hip/hip_runtime.h>

#define HW 1024
#define TWO_PI_F 6.28318530717958647692f
#define NSLOT 64   // atomic spreading: 64 slots per accumulator, 5 accumulators

typedef float v2f __attribute__((ext_vector_type(2)));
typedef int   i2v __attribute__((ext_vector_type(2)));

__device__ __forceinline__ v2f mkv2(float a, float b){ v2f r; r.x = a; r.y = b; return r; }
__device__ __forceinline__ v2f v2s(float s){ v2f r; r.x = s; r.y = s; return r; }

__device__ __forceinline__ float2 cmulf(float2 a, float2 b){
  return make_float2(a.x*b.x - a.y*b.y, a.x*b.y + a.y*b.x);
}
__device__ __forceinline__ float fsqrt(float x){ return __builtin_amdgcn_sqrtf(x); }

// fast |atan2|: caller passes ay = |y| >= 0. Saves the final sign-select.
__device__ __forceinline__ float fast_atan2_abs(float ay, float x){
  float ax = fabsf(x);
  float mx = fmaxf(ax, ay), mn = fminf(ax, ay);
  float a  = mn * __builtin_amdgcn_rcpf(fmaxf(mx, 1e-37f));
  float s  = a * a;
  float r  = ((((0.0208351f*s - 0.085133f)*s + 0.180141f)*s - 0.3302995f)*s
              + 0.999866f) * a;
  r = (ay > ax) ? 1.57079632679f - r : r;
  return (x < 0.f) ? 3.14159265359f - r : r;
}

// 256-thread block reduction (4 waves of 64), float
__device__ __forceinline__ float block_reduce_add_f(float v, float* sc){
  int tid = threadIdx.x;
  #pragma unroll
  for (int o = 32; o > 0; o >>= 1) v += __shfl_down(v, o, 64);
  __syncthreads();
  if ((tid & 63) == 0) sc[tid >> 6] = v;
  __syncthreads();
  return sc[0] + sc[1] + sc[2] + sc[3];
}

// merged setup: zero accumulators + twiddle table (one launch)
__global__ void setup_kernel(double* acc, float2* twg){
  int i = threadIdx.x + blockIdx.x * 256;   // grid 2 x 256 -> 0..511
  if (i < 5 * NSLOT) acc[i] = 0.0;
  if (i < 512){
    float s, c; sincosf(-TWO_PI_F * (float)i * (1.f/1024.f), &s, &c);
    twg[i] = make_float2(c, s);
  }
}

// ---------------------------------------------------------------------------
// Spatial half (R17/R21-verified body; one dispatch per R24 measurement).
// ---------------------------------------------------------------------------
__global__ __launch_bounds__(256, 4)
void spatial_kernel(const float* __restrict__ pred, const float* __restrict__ targ,
                    const float* __restrict__ mask, double* __restrict__ acc){
  __shared__ v2f spt[36*44];               // (pred, targ) halo tile, stride 44
  __shared__ v2f pmt[34*35];               // union: smkf float[38*41] / (pmag,tmag)
  __shared__ unsigned long long mrow[38];
  __shared__ float sc[4];
  float* const smkf = (float*)pmt;         // 1558 floats = 6232 B <= 9520 B

  const int tid = threadIdx.x;
  const int x0 = blockIdx.x << 5, y0 = blockIdx.y << 5;
  const int z = blockIdx.z;
  const size_t ib = (size_t)z * ((size_t)HW * HW);
  const bool interior = ((unsigned)(blockIdx.x - 1) < 30u) &&
                        ((unsigned)(blockIdx.y - 1) < 30u);

  if (interior){
    const float* pb = pred + ib;
    const float* tb = targ + ib;
    for (int i = tid; i < 360; i += 256){        // 36 rows x 10 float4 (40 cols)
      int a = i / 10, b = i % 10;
      size_t off = (size_t)(y0 - 2 + a) * HW + (x0 - 4 + 4*b);
      float4 pv = *(const float4*)(pb + off);
      float4 tv = *(const float4*)(tb + off);
      int o = a*44 + 4*b;
      spt[o+0] = mkv2(pv.x, tv.x);
      spt[o+1] = mkv2(pv.y, tv.y);
      spt[o+2] = mkv2(pv.z, tv.z);
      spt[o+3] = mkv2(pv.w, tv.w);
    }
    const float* mb = mask + ib;
    for (int i = tid; i < 380; i += 256){        // 38 rows x 10 float4
      int a = i / 10, b = i % 10;
      size_t off = (size_t)(y0 - 3 + a) * HW + (x0 - 4 + 4*b);
      float4 v = *(const float4*)(mb + off);
      int o = a*41 + 4*b;
      smkf[o]=v.x; smkf[o+1]=v.y; smkf[o+2]=v.z; smkf[o+3]=v.w;
    }
  } else {
    for (int i = tid; i < 1296; i += 256){
      int a = i / 36, b = i % 36;
      int gy = y0 - 2 + a, gx = x0 - 2 + b;
      float pv = 0.f, tv = 0.f;
      if ((unsigned)gy < HW && (unsigned)gx < HW){
        size_t idx = ib + (size_t)gy * HW + gx;
        pv = pred[idx]; tv = targ[idx];
      }
      spt[a*44 + b + 2] = mkv2(pv, tv);
    }
    for (int i = tid; i < 1444; i += 256){
      int a = i / 38, b = i % 38;
      int gy = y0 - 3 + a, gx = x0 - 3 + b;
      float v = 0.f;
      if ((unsigned)gy < HW && (unsigned)gx < HW) v = mask[ib + (size_t)gy * HW + gx];
      smkf[a*41 + b + 1] = v;
    }
  }
  __syncthreads();

  // wave-parallel mask rows via ballot (lanes 0..37 active per row)
  {
    const int wv = tid >> 6, lane = tid & 63;
    for (int r = wv; r < 38; r += 4){
      float val = (lane < 38) ? smkf[r*41 + 1 + lane] : 0.f;
      unsigned long long m = __ballot(val > 0.5f);
      if (lane == 0) mrow[r] = m;
    }
  }
  __syncthreads();                              // smkf reads done; pmt reuse ok

  if (interior){
    for (int i = tid; i < 1156; i += 256){      // no bounds checks: always in-range
      int iy = i / 34, ix = i % 34;
      int o = iy*44 + ix + 2;
      v2f a00=spt[o],    a01=spt[o+1],  a02=spt[o+2];
      v2f a10=spt[o+44],                a12=spt[o+46];
      v2f a20=spt[o+88], a21=spt[o+89], a22=spt[o+90];
      v2f gx = (a02 + v2s(2.f)*a12 + a22) - (a00 + v2s(2.f)*a10 + a20);
      v2f gy = (a20 + v2s(2.f)*a21 + a22) - (a00 + v2s(2.f)*a01 + a02);
      v2f m2 = gx*gx + gy*gy + v2s(1e-8f);
      pmt[iy*35+ix] = mkv2(fsqrt(m2.x), fsqrt(m2.y));
    }
  } else {
    for (int i = tid; i < 1156; i += 256){
      int iy = i / 34, ix = i % 34;
      int gy = y0 - 1 + iy, gx = x0 - 1 + ix;
      v2f out = v2s(0.f);
      if ((unsigned)gy < HW && (unsigned)gx < HW){
        int o = iy*44 + ix + 2;
        v2f a00=spt[o],    a01=spt[o+1],  a02=spt[o+2];
        v2f a10=spt[o+44],                a12=spt[o+46];
        v2f a20=spt[o+88], a21=spt[o+89], a22=spt[o+90];
        v2f gxv = (a02 + v2s(2.f)*a12 + a22) - (a00 + v2s(2.f)*a10 + a20);
        v2f gyv = (a20 + v2s(2.f)*a21 + a22) - (a00 + v2s(2.f)*a01 + a02);
        v2f m2 = gxv*gxv + gyv*gyv + v2s(1e-8f);
        out = mkv2(fsqrt(m2.x), fsqrt(m2.y));
      }
      pmt[iy*35+ix] = out;
    }
  }
  __syncthreads();

  const int ty = tid >> 5, tx = tid & 31;
  const int r0 = ty << 2;

  // packed counts: cp[j] = c1 | c2<<8 | c3<<16 (vertical sums can't carry)
  int cp[10];
  #pragma unroll
  for (int j = 0; j < 10; j++){
    unsigned w = (unsigned)(mrow[r0 + j] >> tx);
    int c3 = __popc(w & 0x7Fu);
    int c2 = __popc((w >> 1) & 0x1Fu);
    int c1 = __popc((w >> 2) & 0x7u);
    cp[j] = c1 | (c2 << 8) | (c3 << 16);
  }

  v2f PQ[3][3], AB[3][3];
  #pragma unroll
  for (int rr = 0; rr < 2; rr++)
    #pragma unroll
    for (int cc = 0; cc < 3; cc++){
      PQ[rr][cc] = spt[(r0+1+rr)*44 + tx+3+cc];
      AB[rr][cc] = pmt[(r0+rr)*35 + tx+cc];
    }

  // per-row rolling state: slot r <-> PQ row (r0+1+r) / AB row (r0+r)
  v2f wR[6], wA[6];      // (1,2,1)-weighted row sums (sobel-y / slope-y)
  float uR[6], qR[6];    // plain and squared row sums of pred (smooth)
  #pragma unroll
  for (int r = 0; r < 2; r++){
    wR[r] = PQ[r][0] + v2s(2.f)*PQ[r][1] + PQ[r][2];
    float p0 = PQ[r][0].x, p1 = PQ[r][1].x, p2 = PQ[r][2].x;
    uR[r] = p0 + p1 + p2;
    qR[r] = fmaf(p0, p0, fmaf(p1, p1, p2*p2));
    wA[r] = AB[r][0] + v2s(2.f)*AB[r][1] + AB[r][2];
  }

  float accg = 0.f, accs = 0.f, accl = 0.f;
  #pragma unroll
  for (int k = 0; k < 4; k++){
    #pragma unroll
    for (int cc = 0; cc < 3; cc++){
      PQ[2][cc] = spt[(r0+k+3)*44 + tx+3+cc];
      AB[2][cc] = pmt[(r0+k+2)*35 + tx+cc];
    }
    {
      wR[k+2] = PQ[2][0] + v2s(2.f)*PQ[2][1] + PQ[2][2];
      float p0 = PQ[2][0].x, p1 = PQ[2][1].x, p2 = PQ[2][2].x;
      uR[k+2] = p0 + p1 + p2;
      qR[k+2] = fmaf(p0, p0, fmaf(p1, p1, p2*p2));
      wA[k+2] = AB[2][0] + v2s(2.f)*AB[2][1] + AB[2][2];
    }

    v2f gxv = (PQ[0][2] + v2s(2.f)*PQ[1][2] + PQ[2][2]) - (PQ[0][0] + v2s(2.f)*PQ[1][0] + PQ[2][0]);
    v2f gyv = wR[k+2] - wR[k];
    v2f cvv = v2s(4.f)*PQ[1][1] - PQ[0][1] - PQ[1][0] - PQ[1][2] - PQ[2][1];

    float sd = fabsf(AB[1][1].x - AB[1][1].y);
    float x1 = gxv.x + 1e-8f, y1 = gyv.x;
    float x2 = gxv.y + 1e-8f, y2 = gyv.y;
    float dd = fast_atan2_abs(fabsf(y1*x2 - x1*y2), x1*x2 + y1*y2);
    float cd = fabsf(cvv.x - cvv.y);

    int s1p = cp[k+2] + cp[k+3] + cp[k+4];
    int s2p = s1p + cp[k+1] + cp[k+5];
    int s3p = s2p + cp[k]   + cp[k+6];
    int s1 = s1p & 0xFF;
    int s2 = (s2p >> 8) & 0xFF;
    int s3 = s3p >> 16;
    float w1 = ((unsigned)(s1 - 1) <  8u) ? 1.f : 0.f;
    float w2 = ((unsigned)(s2 - 1) < 24u) ? 1.f : 0.f;
    float w3 = ((unsigned)(s3 - 1) < 48u) ? 1.f : 0.f;
    float wa = fmaf(0.5f, w2 + w3, w1);

    accg = fmaf(wa, sd + dd + 2.f*cd, accg);

    float s9 = uR[k] + uR[k+1] + uR[k+2];
    float s9q = qR[k] + qR[k+1] + qR[k+2];
    float lm = s9 * (1.f/9.f), lq = s9q * (1.f/9.f);
    accs = fmaf(fsqrt(fmaxf(lq - lm*lm, 1e-8f)), w1, accs);

    v2f px = (AB[0][2] + v2s(2.f)*AB[1][2] + AB[2][2]) - (AB[0][0] + v2s(2.f)*AB[1][0] + AB[2][0]);
    v2f py = wA[k+2] - wA[k];
    v2f ch2 = px*px + py*py + v2s(1e-8f);
    accl = fmaf(fabsf(fsqrt(ch2.x) - fsqrt(ch2.y)), w1, accl);

    if (k < 3){
      #pragma unroll
      for (int cc = 0; cc < 3; cc++){
        PQ[0][cc] = PQ[1][cc]; PQ[1][cc] = PQ[2][cc];
        AB[0][cc] = AB[1][cc]; AB[1][cc] = AB[2][cc];
      }
    }
  }

  float g  = block_reduce_add_f(accg, sc);
  float sm = block_reduce_add_f(accs, sc);
  float sl = block_reduce_add_f(accl, sc);
  if (tid == 0){
    int slot = (blockIdx.x + blockIdx.y * 7 + z * 13) & (NSLOT - 1);
    atomicAdd(&acc[0*NSLOT + slot], (double)g);
    atomicAdd(&acc[1*NSLOT + slot], (double)sm);
    atomicAdd(&acc[2*NSLOT + slot], (double)sl);
  }
}

// ---------------------------------------------------------------------------
// ALL-VALU lane exchanges (R20-verified primitives).
// ---------------------------------------------------------------------------
template<int CTRL>
__device__ __forceinline__ float xordpp(float x){
  int xi = __float_as_int(x);
  return __int_as_float(__builtin_amdgcn_update_dpp(xi, xi, CTRL, 0xF, 0xF, true));
}
__device__ __forceinline__ float xor4v(float x){
  int xi = __float_as_int(x);
  int t1 = __builtin_amdgcn_update_dpp(xi, xi, 0x104, 0xF, 0x5, false); // SHL4 -> banks 0,2
  int t2 = __builtin_amdgcn_update_dpp(t1, xi, 0x114, 0xF, 0xA, false); // SHR4 -> banks 1,3
  return __int_as_float(t2);
}

#define FC 0.70710678118654752f
#define FC1 0.92387953251128676f
#define FS1 0.38268343236508977f

__device__ __forceinline__ void bfly(float2& a, float2& b){
  float tx = b.x, ty = b.y;
  b.x = a.x - tx; b.y = a.y - ty;
  a.x += tx;      a.y += ty;
}
__device__ __forceinline__ void cmul_c(float2& b, float wr, float wi){
  float tx = wr*b.x - wi*b.y, ty = wr*b.y + wi*b.x;
  b.x = tx; b.y = ty;
}
__device__ __forceinline__ void rotmi(float2& b){   // b *= -i
  float t = b.x; b.x = b.y; b.y = -t;
}

__device__ __forceinline__ void fft16_reg(float2* v){
  float2 y[16];
  y[0]=v[0];  y[1]=v[8];  y[2]=v[4];  y[3]=v[12];
  y[4]=v[2];  y[5]=v[10]; y[6]=v[6];  y[7]=v[14];
  y[8]=v[1];  y[9]=v[9];  y[10]=v[5]; y[11]=v[13];
  y[12]=v[3]; y[13]=v[11];y[14]=v[7]; y[15]=v[15];
  #pragma unroll
  for (int g = 0; g < 8; g++) bfly(y[2*g], y[2*g+1]);
  #pragma unroll
  for (int g = 0; g < 4; g++){
    int b = 4*g;
    bfly(y[b], y[b+2]);
    rotmi(y[b+3]); bfly(y[b+1], y[b+3]);
  }
  #pragma unroll
  for (int g = 0; g < 2; g++){
    int b = 8*g;
    bfly(y[b], y[b+4]);
    cmul_c(y[b+5],  FC, -FC); bfly(y[b+1], y[b+5]);
    rotmi(y[b+6]);            bfly(y[b+2], y[b+6]);
    cmul_c(y[b+7], -FC, -FC); bfly(y[b+3], y[b+7]);
  }
  bfly(y[0], y[8]);
  cmul_c(y[9],   FC1, -FS1); bfly(y[1], y[9]);
  cmul_c(y[10],  FC,  -FC);  bfly(y[2], y[10]);
  cmul_c(y[11],  FS1, -FC1); bfly(y[3], y[11]);
  rotmi(y[12]);              bfly(y[4], y[12]);
  cmul_c(y[13], -FS1, -FC1); bfly(y[5], y[13]);
  cmul_c(y[14], -FC,  -FC);  bfly(y[6], y[14]);
  cmul_c(y[15], -FC1, -FS1); bfly(y[7], y[15]);
  #pragma unroll
  for (int j = 0; j < 16; j++) v[j] = y[j];
}

// ---------------------------------------------------------------------------
// Natural-lane DIT (R22-verified): logical lane L = brev6(p); natural input
// order; six verified exchange primitives in reversed order; output
// X[brev6(p)+64j]. Twiddles from table (R26-measured fastest variant).
// ---------------------------------------------------------------------------
__device__ __forceinline__ void fft1024_wave(float2* v, int lane /*logical L*/,
                                             const float2* __restrict__ twg){
  const float2 tw1 = twg[(lane & 1) << 8];
  const float2 tw2 = twg[(lane & 3) << 7];
  const float2 tw3 = twg[(lane & 7) << 6];
  const float2 tw4 = twg[(lane & 15) << 5];
  const float2 tw5 = twg[(lane & 31) << 4];
  const float2 wq  = twg[lane];

  // stage 0 (logical h=1 -> physical 32): permlane32 fused, w=1
  {
    const float sgn = (lane & 1) ? -1.f : 1.f;
    #pragma unroll
    for (int j = 0; j < 16; j++){
      i2v px = __builtin_amdgcn_permlane32_swap(__float_as_int(v[j].x), __float_as_int(v[j].x), false, false);
      i2v py = __builtin_amdgcn_permlane32_swap(__float_as_int(v[j].y), __float_as_int(v[j].y), false, false);
      v[j].x = fmaf(sgn, __int_as_float(px.y), __int_as_float(px.x));
      v[j].y = fmaf(sgn, __int_as_float(py.y), __int_as_float(py.x));
    }
  }
  // stage 1 (logical h=2 -> physical 16): permlane16 fused
  {
    const bool up = (lane & 2) != 0;
    const float ewx = up ? tw1.x : 1.f, ewy = up ? tw1.y : 0.f;
    const float sgn = up ? -1.f : 1.f;
    #pragma unroll
    for (int j = 0; j < 16; j++){
      float tx = ewx*v[j].x - ewy*v[j].y;
      float ty = ewx*v[j].y + ewy*v[j].x;
      i2v px = __builtin_amdgcn_permlane16_swap(__float_as_int(tx), __float_as_int(tx), false, false);
      i2v py = __builtin_amdgcn_permlane16_swap(__float_as_int(ty), __float_as_int(ty), false, false);
      v[j].x = fmaf(sgn, __int_as_float(px.y), __int_as_float(px.x));
      v[j].y = fmaf(sgn, __int_as_float(py.y), __int_as_float(py.x));
    }
  }
  // stage 2 (logical h=4 -> physical 8): ROW_ROR:8
  {
    const bool up = (lane & 4) != 0;
    const float ewx = up ? tw2.x : 1.f, ewy = up ? tw2.y : 0.f;
    const float sgn = up ? -1.f : 1.f;
    #pragma unroll
    for (int j = 0; j < 16; j++){
      float tx = ewx*v[j].x - ewy*v[j].y;
      float ty = ewx*v[j].y + ewy*v[j].x;
      v[j].x = fmaf(sgn, tx, xordpp<0x128>(tx));
      v[j].y = fmaf(sgn, ty, xordpp<0x128>(ty));
    }
  }
  // stage 3 (logical h=8 -> physical 4): bank-masked DPP pair
  {
    const bool up = (lane & 8) != 0;
    const float ewx = up ? tw3.x : 1.f, ewy = up ? tw3.y : 0.f;
    const float sgn = up ? -1.f : 1.f;
    #pragma unroll
    for (int j = 0; j < 16; j++){
      float tx = ewx*v[j].x - ewy*v[j].y;
      float ty = ewx*v[j].y + ewy*v[j].x;
      v[j].x = fmaf(sgn, tx, xor4v(tx));
      v[j].y = fmaf(sgn, ty, xor4v(ty));
    }
  }
  // stage 4 (logical h=16 -> physical 2): quad_perm xor2
  {
    const bool up = (lane & 16) != 0;
    const float ewx = up ? tw4.x : 1.f, ewy = up ? tw4.y : 0.f;
    const float sgn = up ? -1.f : 1.f;
    #pragma unroll
    for (int j = 0; j < 16; j++){
      float tx = ewx*v[j].x - ewy*v[j].y;
      float ty = ewx*v[j].y + ewy*v[j].x;
      v[j].x = fmaf(sgn, tx, xordpp<0x4E>(tx));
      v[j].y = fmaf(sgn, ty, xordpp<0x4E>(ty));
    }
  }
  // stage 5 (logical h=32 -> physical 1): quad_perm xor1
  {
    const bool up = (lane & 32) != 0;
    const float ewx = up ? tw5.x : 1.f, ewy = up ? tw5.y : 0.f;
    const float sgn = up ? -1.f : 1.f;
    #pragma unroll
    for (int j = 0; j < 16; j++){
      float tx = ewx*v[j].x - ewy*v[j].y;
      float ty = ewx*v[j].y + ewy*v[j].x;
      v[j].x = fmaf(sgn, tx, xordpp<0xB1>(tx));
      v[j].y = fmaf(sgn, ty, xordpp<0xB1>(ty));
    }
  }
  // per-slot twiddle: v[j] *= wq^j; log-depth powers
  float2 w2 = cmulf(wq, wq);
  float2 w3 = cmulf(w2, wq);
  float2 w4 = cmulf(w2, w2);
  float2 w5 = cmulf(w3, w2);
  float2 w6 = cmulf(w3, w3);
  float2 w7 = cmulf(w4, w3);
  float2 w8 = cmulf(w4, w4);
  v[1]  = cmulf(v[1],  wq);
  v[2]  = cmulf(v[2],  w2);
  v[3]  = cmulf(v[3],  w3);
  v[4]  = cmulf(v[4],  w4);
  v[5]  = cmulf(v[5],  w5);
  v[6]  = cmulf(v[6],  w6);
  v[7]  = cmulf(v[7],  w7);
  v[8]  = cmulf(v[8],  w8);
  v[9]  = cmulf(cmulf(v[9],  w8), wq);
  v[10] = cmulf(cmulf(v[10], w8), w2);
  v[11] = cmulf(cmulf(v[11], w8), w3);
  v[12] = cmulf(cmulf(v[12], w8), w4);
  v[13] = cmulf(cmulf(v[13], w8), w5);
  v[14] = cmulf(cmulf(v[14], w8), w6);
  v[15] = cmulf(cmulf(v[15], w8), w7);
  fft16_reg(v);
}

// ---------------------------------------------------------------------------
// FFT pass 1 + tiled transpose. Natural-lane coalesced loads; Zt storage row
// rr holds spectral pi(rr) = (rr&960)|brev6(rr&63) (involution).
// ---------------------------------------------------------------------------
__global__ __launch_bounds__(512, 2)
void fft_rows_t_kernel(const float* __restrict__ pred, const float* __restrict__ targ,
                       float2* __restrict__ Zt, const float2* __restrict__ twg){
  __shared__ float2 tile[8][64][9];
  const int tid = threadIdx.x;
  const int lane = tid & 63;
  const int w = tid >> 6;
  const int y0 = blockIdx.x << 3;
  const size_t ibase = ((size_t)blockIdx.y * HW + (y0 + w)) * HW;
  const int rb = __brev(lane) >> 26;           // logical lane for the FFT
  const float4* p4 = (const float4*)(pred + ibase);
  const float4* t4 = (const float4*)(targ + ibase);
  float2 v[16];
  #pragma unroll
  for (int m = 0; m < 4; m++){
    float4 a = p4[4*lane + m];                 // natural order: x[16*lane + 4m ..]
    float4 b = t4[4*lane + m];
    v[4*m+0] = make_float2(a.x, b.x);
    v[4*m+1] = make_float2(a.y, b.y);
    v[4*m+2] = make_float2(a.z, b.z);
    v[4*m+3] = make_float2(a.w, b.w);
  }
  fft1024_wave(v, rb, twg);
  float2* zb = Zt + (size_t)blockIdx.y * HW * HW + (size_t)blockIdx.x * 8192;
  const int yl = tid & 7, kl = tid >> 3;
  #pragma unroll
  for (int jb = 0; jb < 2; jb++){
    __syncthreads();
    #pragma unroll
    for (int jj = 0; jj < 8; jj++) tile[jj][lane][w] = v[8*jb + jj];
    __syncthreads();
    #pragma unroll
    for (int jj = 0; jj < 8; jj++){
      int k = ((jb << 3) + jj) * 64 + kl;      // storage row; spectral = pi(row)
      zb[k * 8 + yl] = tile[jj][kl][yl];       // contiguous across the block
    }
  }
}

// ---------------------------------------------------------------------------
// FFT pass 2 + reduce (R23-verified structure: early returns, LDS exactly
// 32768 B -> 5 blocks/CU; separate finalize dispatch).
// ---------------------------------------------------------------------------
__device__ __forceinline__ void freq_contrib(float2 Zk, float2 Zm, int k1, int k2,
                                             float& ms, float& ps){
  int di = k1 - 512, dj = k2 - 512;
  if (di*di + dj*dj < 94372) return;         // dist > 307.2  <=>  r2 >= 94372
  float pr = 0.5f*(Zk.x + Zm.x);
  float pi = 0.5f*(Zk.y - Zm.y);
  float tr = 0.5f*(Zk.y + Zm.y);
  float ti = 0.5f*(Zm.x - Zk.x);
  float p2 = pr*pr + pi*pi;
  float t2 = tr*tr + ti*ti;
  ms += p2 + t2 - 2.f*fsqrt(p2*t2);
  float re = pr*tr + pi*ti;
  float im = pi*tr - pr*ti;
  float pd = fast_atan2_abs(fabsf(im), re);  // squared below; sign irrelevant
  ps += pd*pd;
}

__global__ __launch_bounds__(256, 2)
void fft_cols2_kernel(const float2* __restrict__ Z, const float2* __restrict__ twg,
                      double* __restrict__ acc){
  __shared__ float2 ex[4][1024];            // per-wave natural-order spectrum
  const int lane = threadIdx.x & 63;
  const int w = threadIdx.x >> 6;           // 0..3
  const int p = 2 * blockIdx.x + (w >> 1);  // pair index, 0..512 valid
  const bool valid = (p <= 512);
  const int r_spec = (w & 1) ? ((1024 - p) & 1023) : p;   // spectral row (k1)
  const int rr = (r_spec & 0x3C0) | (__brev(r_spec & 63) >> 26); // Zt storage row
  const float2* base = Z + (size_t)blockIdx.y * HW * HW;
  const int bl = __brev(lane) >> 26;        // logical lane for the FFT

  float2 v[16];
  if (valid){
    const float4* f4 = (const float4*)base;
    #pragma unroll
    for (int s = 0; s < 2; s++){
      size_t o = (size_t)(2*lane + s) * 4096 + (size_t)rr * 4;  // float4 units
      #pragma unroll
      for (int q = 0; q < 4; q++){
        float4 x = f4[o + q];
        v[8*s + 2*q]     = make_float2(x.x, x.y);
        v[8*s + 2*q + 1] = make_float2(x.z, x.w);
      }
    }
    fft1024_wave(v, bl, twg);
    #pragma unroll
    for (int j = 0; j < 16; j++) ex[w][bl + (j << 6)] = v[j];   // natural order
  }
  __syncthreads();
  if (!valid) return;
  const bool self = (p == 0) || (p == 512);
  if ((w & 1) && self) return;              // duplicate row: LDS written, no contribs

  const float2* pb = ex[w ^ 1];             // partner spectrum, natural order
  float ms = 0.f, ps = 0.f;
  #pragma unroll
  for (int j = 0; j < 16; j++){
    int k = bl + (j << 6);                  // this value's spectral index k2
    float2 zm = pb[(1024 - k) & 1023];      // Z_partner(-k)
    freq_contrib(v[j], zm, k, r_spec, ms, ps);
  }
  #pragma unroll
  for (int o = 32; o > 0; o >>= 1){
    ms += __shfl_down(ms, o, 64);
    ps += __shfl_down(ps, o, 64);
  }
  if (lane == 0){
    int slot = (r_spec + blockIdx.y * 11) & (NSLOT - 1);
    atomicAdd(&acc[3*NSLOT + slot], (double)ms);
    atomicAdd(&acc[4*NSLOT + slot], (double)ps);
  }
}

// ---------------------------------------------------------------------------
__global__ void finalize_kernel(const double* __restrict__ acc, float* __restrict__ out){
  const int t = threadIdx.x;   // 64 threads
  double v[5];
  #pragma unroll
  for (int s = 0; s < 5; s++) v[s] = acc[s*NSLOT + t];
  #pragma unroll
  for (int o = 32; o > 0; o >>= 1)
    #pragma unroll
    for (int s = 0; s < 5; s++) v[s] += __shfl_down(v[s], o, 64);
  if (t == 0){
    const double inv = 1.0 / 8388608.0;      // mean over 8*1024*1024
    double grad   = v[0] * inv / 3.0;        // / len(bms)
    double smooth = v[1] * inv;
    double slope  = v[2] * inv;
    double freq   = (v[3] + 2.0 * v[4]) * inv;
    double total  = 2.0*grad + 1.5*freq + 3.0*smooth + 2.0*slope;
    out[0] = (float)total;
    out[1] = (float)grad;
    out[2] = (float)freq;
    out[3] = (float)smooth;
    out[4] = (float)slope;
  }
}

extern "C" void kernel_launch(void* const* d_in, const int* in_sizes, int n_in,
                              void* d_out, int out_size, void* d_ws, size_t ws_size,
                              hipStream_t stream){
  const float* pred = (const float*)d_in[0];
  const float* targ = (const float*)d_in[1];
  const float* mask = (const float*)d_in[2];
  double* acc  = (double*)d_ws;                         // [0, 2560)
  float2* twg  = (float2*)((char*)d_ws + 4096);         // [4096, 8192)
  float2* Z    = (float2*)((char*)d_ws + 8192);         // 8 x 8 MiB fp32 images

  // R27: fork/join — spatial (VALU-bound) runs concurrently with rows->cols
  // (latency-bound, complementary resources; disjoint acc ranges; Z private).
  static hipStream_t s2 = nullptr;
  static hipEvent_t evFork = nullptr, evJoin = nullptr;
  if (s2 == nullptr){
    hipStreamCreateWithFlags(&s2, hipStreamNonBlocking);
    hipEventCreateWithFlags(&evFork, hipEventDisableTiming);
    hipEventCreateWithFlags(&evJoin, hipEventDisableTiming);
  }

  setup_kernel<<<2, 256, 0, stream>>>(acc, twg);
  hipEventRecord(evFork, stream);
  hipStreamWaitEvent(s2, evFork, 0);
  fft_rows_t_kernel<<<dim3(128, 8), 512, 0, s2>>>(pred, targ, Z, twg);
  fft_cols2_kernel<<<dim3(257, 8), 256, 0, s2>>>(Z, twg, acc);
  hipEventRecord(evJoin, s2);
  spatial_kernel<<<dim3(32, 32, 8), 256, 0, stream>>>(pred, targ, mask, acc);
  hipStreamWaitEvent(stream, evJoin, 0);
  finalize_kernel<<<1, 64, 0, stream>>>(acc, (float*)d_out);
}